// Round 8
// baseline (437.019 us; speedup 1.0000x reference)
//
#include <hip/hip_runtime.h>
#include <hip/hip_bf16.h>

#define NN 100000
#define EE 1600000
#define DD 128
#define GG 128
#define CC 10
#define NPB 256      // nodes per bucket (power of 2)
#define NB 391       // ceil(NN/NPB)
#define SCAP 5120    // LDS slot capacity per bucket (mean 4092, sigma ~64)
#define VPT 16       // edges per thread in k_bcount/k_part
#define CPAD 32      // padded counter stride (ints) = 128B per counter
#define PPN 64       // nodes per pool block

typedef __attribute__((ext_vector_type(8))) short bf16x8;
typedef __attribute__((ext_vector_type(4))) float f32x4;
typedef unsigned int u32;

__device__ inline float blo(u32 u) { return __uint_as_float(u << 16); }
__device__ inline float bhi(u32 u) { return __uint_as_float(u & 0xffff0000u); }
// pack two floats to bf16x2 (RNE)
__device__ inline u32 bpack(float x, float y) {
    u32 bx = __float_as_uint(x);
    u32 by = __float_as_uint(y);
    bx = (bx + 0x7fffu + ((bx >> 16) & 1u)) >> 16;
    by = (by + 0x7fffu + ((by >> 16) & 1u)) & 0xffff0000u;
    return bx | by;
}

// ---------- bucket histogram: block-aggregated, padded counters ----------
__global__ __launch_bounds__(256) void k_bcount(const int* __restrict__ col,
                                                int* __restrict__ bhist) {
    __shared__ int lh[NB];
    int tid = threadIdx.x;
    for (int b = tid; b < NB; b += 256) lh[b] = 0;
    __syncthreads();
    int base = blockIdx.x * (256 * VPT);
#pragma unroll
    for (int j = 0; j < VPT; j++) {
        int e = base + j * 256 + tid;
        if (e < EE) atomicAdd(&lh[col[e] >> 8], 1);
    }
    __syncthreads();
    for (int b = tid; b < NB; b += 256) {
        int h = lh[b];
        if (h) atomicAdd(&bhist[b * CPAD], h);
    }
}

// ---------- bucket exclusive scan (single block, 512 threads) ----------
__global__ __launch_bounds__(512) void k_bscan(const int* __restrict__ bhist,
                                               int* __restrict__ boffs,
                                               int* __restrict__ bcur) {
    __shared__ int s[512];
    int tid = threadIdx.x;
    int c = (tid < NB) ? bhist[tid * CPAD] : 0;
    s[tid] = c;
    __syncthreads();
    for (int off = 1; off < 512; off <<= 1) {
        int v = (tid >= off) ? s[tid - off] : 0;
        __syncthreads();
        s[tid] += v;
        __syncthreads();
    }
    int excl = s[tid] - c;
    if (tid < NB) {
        boffs[tid] = excl;
        bcur[tid * CPAD] = excl;
    }
    if (tid == NB - 1) boffs[NB] = excl + c;  // == EE
}

// ---------- partition edges into bucket regions (packed r<<8 | c&255) ----------
__global__ __launch_bounds__(256) void k_part(const int* __restrict__ row, const int* __restrict__ col,
                                              int* __restrict__ bcur, u32* __restrict__ pairs) {
    __shared__ int lhist[NB];
    __shared__ int gbase[NB];
    __shared__ int lcur[NB];
    int tid = threadIdx.x;
    for (int b = tid; b < NB; b += 256) lhist[b] = 0;
    __syncthreads();
    int base = blockIdx.x * (256 * VPT);
    u32 v[VPT];
    int bb[VPT];
#pragma unroll
    for (int j = 0; j < VPT; j++) {
        int e = base + j * 256 + tid;
        if (e < EE) {
            int r = row[e], c = col[e];
            v[j] = ((u32)r << 8) | (u32)(c & 255);
            bb[j] = c >> 8;
            atomicAdd(&lhist[bb[j]], 1);
        } else {
            bb[j] = -1;
        }
    }
    __syncthreads();
    for (int b = tid; b < NB; b += 256) {
        int h = lhist[b];
        gbase[b] = h ? atomicAdd(&bcur[b * CPAD], h) : 0;
        lcur[b] = 0;
    }
    __syncthreads();
#pragma unroll
    for (int j = 0; j < VPT; j++) {
        if (bb[j] >= 0) {
            int slot = gbase[bb[j]] + atomicAdd(&lcur[bb[j]], 1);
            pairs[slot] = v[j];
        }
    }
}

// ---------- per-bucket: node counts -> offs+dis, LDS counting sort -> src ----------
__global__ __launch_bounds__(256) void k_sort(const u32* __restrict__ pairs,
                                              const int* __restrict__ boffs,
                                              int* __restrict__ offs,
                                              float* __restrict__ dis,
                                              int* __restrict__ src) {
    int b = blockIdx.x;
    int tid = threadIdx.x;
    int nstart = b << 8;
    int nvalid = NN - nstart;           // valid nodes in this bucket
    if (nvalid > NPB) nvalid = NPB;
    int base = boffs[b];
    int eend = boffs[b + 1];
    int cnt = eend - base;
    __shared__ int lcnt[NPB];
    __shared__ int lscan[NPB];
    __shared__ int lcur[NPB];
    __shared__ int lsrc[SCAP];
    lcnt[tid] = 0;
    __syncthreads();
    for (int e = base + tid; e < eend; e += 256)
        atomicAdd(&lcnt[pairs[e] & 255u], 1);
    __syncthreads();
    int c = lcnt[tid];
    lscan[tid] = c;
    __syncthreads();
    for (int off = 1; off < 256; off <<= 1) {
        int v = (tid >= off) ? lscan[tid - off] : 0;
        __syncthreads();
        lscan[tid] += v;
        __syncthreads();
    }
    int excl = lscan[tid] - c;
    if (tid < nvalid) {
        offs[nstart + tid] = base + excl;
        dis[nstart + tid] = rsqrtf((float)(c + 1));  // degree includes self-loop
    }
    if (b == NB - 1 && tid == 255) offs[NN] = EE;
    lcur[tid] = excl;
    __syncthreads();
    if (cnt <= SCAP) {
        for (int e = base + tid; e < eend; e += 256) {
            u32 v = pairs[e];
            int slot = atomicAdd(&lcur[v & 255u], 1);
            lsrc[slot] = (int)(v >> 8);
        }
        __syncthreads();
        for (int i = tid; i < cnt; i += 256)
            src[base + i] = lsrc[i];
    } else {
        // fallback (not expected on this input): place directly to global
        for (int e = base + tid; e < eend; e += 256) {
            u32 v = pairs[e];
            int slot = base + atomicAdd(&lcur[v & 255u], 1);
            src[slot] = (int)(v >> 8);
        }
    }
}

// ---------- params prep: W^T -> bf16 with BN scale folded into columns ----------
__global__ void k_prep(const float* __restrict__ Wc, const float* __restrict__ bc,
                       const float* __restrict__ gamma, const float* __restrict__ beta,
                       const float* __restrict__ mean, const float* __restrict__ var,
                       __hip_bfloat16* __restrict__ WT,
                       float* __restrict__ tc) {
    int i = blockIdx.x * 256 + threadIdx.x;
    if (i < 3 * 128) {
        int l = i >> 7, d = i & 127;
        float t;
        if (l < 2) {
            float s = gamma[l * 128 + d] * rsqrtf(var[l * 128 + d] + 1e-5f);
            t = (bc[l * 128 + d] - mean[l * 128 + d]) * s + beta[l * 128 + d];
        } else {
            t = bc[2 * 128 + d];
        }
        tc[i] = t;
    }
    if (i < 3 * 16384) {
        int l = i >> 14, r = (i >> 7) & 127, k = i & 127;
        float s = 1.f;
        if (l < 2) s = gamma[l * 128 + r] * rsqrtf(var[l * 128 + r] + 1e-5f);
        // WT[l][r][k] = W[l][k][r] * sc[l][r]  (BN scale folded into output column)
        WT[i] = __float2bfloat16(Wc[l * 16384 + k * 128 + r] * s);
    }
}

// ---------- GEMM: hs[N,128] = dis[n] * (A[N,128] @ (W*sc)), bf16 MFMA ----------
template <int FP32IN>
__global__ __launch_bounds__(256) void k_gemm(const void* __restrict__ Ain,
                                              const __hip_bfloat16* __restrict__ WT,
                                              const float* __restrict__ dis,
                                              __hip_bfloat16* __restrict__ Cout) {
    int wave = threadIdx.x >> 6, lane = threadIdx.x & 63;
    int lg = lane >> 4, lr = lane & 15;
    int r0w = blockIdx.x * 64 + wave * 16;
    f32x4 zero = {0.f, 0.f, 0.f, 0.f};
    f32x4 acc[8];
#pragma unroll
    for (int ct = 0; ct < 8; ct++) acc[ct] = zero;

    int arow = r0w + lr;
    if (arow > NN - 1) arow = NN - 1;

#pragma unroll
    for (int kk = 0; kk < 4; kk++) {
        bf16x8 a;
        if (FP32IN) {
            const float* ap = (const float*)Ain + (size_t)arow * 128 + kk * 32 + lg * 8;
            float4 f0 = *(const float4*)ap;
            float4 f1 = *(const float4*)(ap + 4);
            u32 t0 = bpack(f0.x, f0.y), t1 = bpack(f0.z, f0.w);
            u32 t2 = bpack(f1.x, f1.y), t3 = bpack(f1.z, f1.w);
            uint4 t = make_uint4(t0, t1, t2, t3);
            a = *(bf16x8*)&t;
        } else {
            a = *(const bf16x8*)((const __hip_bfloat16*)Ain + (size_t)arow * 128 + kk * 32 + lg * 8);
        }
#pragma unroll
        for (int ct = 0; ct < 8; ct++) {
            bf16x8 b = *(const bf16x8*)(WT + (size_t)(ct * 16 + lr) * 128 + kk * 32 + lg * 8);
            acc[ct] = __builtin_amdgcn_mfma_f32_16x16x32_bf16(a, b, acc[ct], 0, 0, 0);
        }
    }
    // C/D layout: col = lane&15, row = (lane>>4)*4 + reg
    float dv[4];
#pragma unroll
    for (int r = 0; r < 4; r++) {
        int row = r0w + lg * 4 + r;
        dv[r] = (row < NN) ? dis[row] : 0.f;
    }
#pragma unroll
    for (int ct = 0; ct < 8; ct++) {
#pragma unroll
        for (int r = 0; r < 4; r++) {
            int row = r0w + lg * 4 + r;
            if (row < NN) Cout[(size_t)row * 128 + ct * 16 + lr] = __float2bfloat16(acc[ct][r] * dv[r]);
        }
    }
}

// ---------- aggregation: h_out = LReLU(dis[c]*(sum(hs[src]) + hs[c]) + tc) ----------
// one wave per node; 16 lanes cover a 256B row via dwordx4, 4 edges per pass.
__global__ __launch_bounds__(256) void k_agg(const uint4* __restrict__ hin,
                                             const int* __restrict__ offs,
                                             const int* __restrict__ src,
                                             const float* __restrict__ dis,
                                             const float* __restrict__ tc,
                                             uint4* __restrict__ hout) {
    int node = (blockIdx.x << 2) + (threadIdx.x >> 6);
    int lane = threadIdx.x & 63;
    int quad = lane >> 4, sub = lane & 15;
    if (node >= NN) return;
    int e0 = __builtin_amdgcn_readfirstlane(offs[node]);
    int e1 = __builtin_amdgcn_readfirstlane(offs[node + 1]);
    float a0 = 0.f, a1 = 0.f, a2 = 0.f, a3 = 0.f, a4 = 0.f, a5 = 0.f, a6 = 0.f, a7 = 0.f;
    if (quad == 0) {  // self-loop contribution once
        uint4 u = hin[(u32)node * 16u + sub];
        a0 = blo(u.x); a1 = bhi(u.x); a2 = blo(u.y); a3 = bhi(u.y);
        a4 = blo(u.z); a5 = bhi(u.z); a6 = blo(u.w); a7 = bhi(u.w);
    }
    for (int e = e0; e < e1; e += 8) {
        int lim = e1 - e;  // wave-uniform
#pragma unroll
        for (int j = 0; j < 2; j++) {
            int idx = j * 4 + quad;
            if (idx < lim) {
                int s = src[e + idx];
                uint4 u = hin[(u32)s * 16u + sub];
                a0 += blo(u.x); a1 += bhi(u.x);
                a2 += blo(u.y); a3 += bhi(u.y);
                a4 += blo(u.z); a5 += bhi(u.z);
                a6 += blo(u.w); a7 += bhi(u.w);
            }
        }
    }
    // combine quads (columns identical across quads)
    a0 += __shfl_xor(a0, 16); a0 += __shfl_xor(a0, 32);
    a1 += __shfl_xor(a1, 16); a1 += __shfl_xor(a1, 32);
    a2 += __shfl_xor(a2, 16); a2 += __shfl_xor(a2, 32);
    a3 += __shfl_xor(a3, 16); a3 += __shfl_xor(a3, 32);
    a4 += __shfl_xor(a4, 16); a4 += __shfl_xor(a4, 32);
    a5 += __shfl_xor(a5, 16); a5 += __shfl_xor(a5, 32);
    a6 += __shfl_xor(a6, 16); a6 += __shfl_xor(a6, 32);
    a7 += __shfl_xor(a7, 16); a7 += __shfl_xor(a7, 32);
    if (quad == 0) {
        float dn = dis[node];
        int d0 = sub * 8;
        float4 t0 = *(const float4*)&tc[d0];
        float4 t1 = *(const float4*)&tc[d0 + 4];
        float r0 = a0 * dn + t0.x, r1 = a1 * dn + t0.y;
        float r2 = a2 * dn + t0.z, r3 = a3 * dn + t0.w;
        float r4 = a4 * dn + t1.x, r5 = a5 * dn + t1.y;
        float r6 = a6 * dn + t1.z, r7 = a7 * dn + t1.w;
        r0 = r0 > 0.f ? r0 : 0.03f * r0; r1 = r1 > 0.f ? r1 : 0.03f * r1;
        r2 = r2 > 0.f ? r2 : 0.03f * r2; r3 = r3 > 0.f ? r3 : 0.03f * r3;
        r4 = r4 > 0.f ? r4 : 0.03f * r4; r5 = r5 > 0.f ? r5 : 0.03f * r5;
        r6 = r6 > 0.f ? r6 : 0.03f * r6; r7 = r7 > 0.f ? r7 : 0.03f * r7;
        uint4 o;
        o.x = bpack(r0, r1); o.y = bpack(r2, r3);
        o.z = bpack(r4, r5); o.w = bpack(r6, r7);
        hout[(u32)node * 16u + sub] = o;
    }
}

// ---------- global mean pool: parallel partial sums (batch sorted) ----------
__global__ __launch_bounds__(64) void k_pool(const u32* __restrict__ h,
                                             const int* __restrict__ batch,
                                             float* __restrict__ pooled,
                                             float* __restrict__ counts) {
    int lane = threadIdx.x;  // covers 2 feature cols
    int n0 = blockIdx.x * PPN;
    if (n0 >= NN) return;
    int n1 = n0 + PPN;
    if (n1 > NN) n1 = NN;
    float a0 = 0.f, a1 = 0.f, cnt = 0.f;
    int g = batch[n0];
    for (int n = n0; n < n1; n++) {
        int bg = batch[n];
        if (bg != g) {
            atomicAdd(&pooled[g * 128 + lane * 2], a0);
            atomicAdd(&pooled[g * 128 + lane * 2 + 1], a1);
            if (lane == 0) atomicAdd(&counts[g], cnt);
            a0 = 0.f; a1 = 0.f; cnt = 0.f; g = bg;
        }
        u32 u = h[(u32)n * 64u + lane];
        a0 += blo(u); a1 += bhi(u);
        cnt += 1.f;
    }
    atomicAdd(&pooled[g * 128 + lane * 2], a0);
    atomicAdd(&pooled[g * 128 + lane * 2 + 1], a1);
    if (lane == 0) atomicAdd(&counts[g], cnt);
}

// ---------- head ----------
__global__ void k_head(const float* __restrict__ pooled, const float* __restrict__ counts,
                       const float* __restrict__ w, const float* __restrict__ b,
                       float* __restrict__ out) {
    int i = blockIdx.x * blockDim.x + threadIdx.x;
    if (i >= GG * CC) return;
    int g = i / CC, c = i % CC;
    float cnt = counts[g];
    cnt = cnt > 1.f ? cnt : 1.f;
    float inv = 1.f / cnt;
    const float* p = &pooled[g * 128];
    const float* ww = &w[c * 128];
    float acc = 0.f;
    for (int d = 0; d < 128; d++) acc += p[d] * ww[d];
    out[i] = acc * inv + b[c];
}

extern "C" void kernel_launch(void* const* d_in, const int* in_sizes, int n_in,
                              void* d_out, int out_size, void* d_ws, size_t ws_size,
                              hipStream_t stream) {
    const float* x     = (const float*)d_in[0];
    const int*   ei    = (const int*)d_in[1];
    const int*   row   = ei;
    const int*   col   = ei + EE;
    const int*   batch = (const int*)d_in[2];
    const float* Wc    = (const float*)d_in[3];
    const float* bc    = (const float*)d_in[4];
    const float* gamma = (const float*)d_in[5];
    const float* beta  = (const float*)d_in[6];
    const float* mean  = (const float*)d_in[7];
    const float* var   = (const float*)d_in[8];
    const float* lw    = (const float*)d_in[9];
    const float* lb    = (const float*)d_in[10];
    float* out = (float*)d_out;

    char* p = (char*)d_ws;
    auto alloc = [&](size_t bytes) -> char* {
        char* r = p;
        p += (bytes + 255) & ~(size_t)255;
        return r;
    };
    float* dis    = (float*)alloc((size_t)NN * 4);
    int*   offs   = (int*)alloc((size_t)(NN + 1) * 4);
    int*   bhist  = (int*)alloc((size_t)NB * CPAD * 4);
    int*   boffs  = (int*)alloc((size_t)(NB + 1) * 4);
    int*   bcur   = (int*)alloc((size_t)NB * CPAD * 4);
    int*   src    = (int*)alloc((size_t)EE * 4);
    __hip_bfloat16* WT = (__hip_bfloat16*)alloc((size_t)3 * 16384 * 2);
    float* tc     = (float*)alloc((size_t)3 * 128 * 4);
    float* pooled = (float*)alloc((size_t)GG * 128 * 4);
    float* counts = (float*)alloc((size_t)GG * 4);
    __hip_bfloat16* h0b = (__hip_bfloat16*)alloc((size_t)NN * 128 * 2);
    __hip_bfloat16* h1b = (__hip_bfloat16*)alloc((size_t)NN * 128 * 2);
    u32* pairs = (u32*)h0b;  // alias: pairs dead before first k_gemm writes h0b

    hipMemsetAsync(bhist, 0, (size_t)NB * CPAD * 4, stream);
    hipMemsetAsync(pooled, 0, (size_t)GG * 128 * 4, stream);
    hipMemsetAsync(counts, 0, (size_t)GG * 4, stream);

    const int eb_grid = (EE + 256 * VPT - 1) / (256 * VPT);
    k_bcount<<<eb_grid, 256, 0, stream>>>(col, bhist);
    k_bscan<<<1, 512, 0, stream>>>(bhist, boffs, bcur);
    k_part<<<eb_grid, 256, 0, stream>>>(row, col, bcur, pairs);
    k_sort<<<NB, 256, 0, stream>>>(pairs, boffs, offs, dis, src);
    k_prep<<<192, 256, 0, stream>>>(Wc, bc, gamma, beta, mean, var, WT, tc);

    const int gemm_grid = (NN + 63) / 64;
    const int agg_grid  = (NN + 3) / 4;

    // layer 0: A = x (fp32)
    k_gemm<1><<<gemm_grid, 256, 0, stream>>>((const void*)x, WT, dis, h0b);
    k_agg<<<agg_grid, 256, 0, stream>>>((const uint4*)h0b, offs, src, dis, tc, (uint4*)h1b);
    // layer 1
    k_gemm<0><<<gemm_grid, 256, 0, stream>>>((const void*)h1b, WT + 16384, dis, h0b);
    k_agg<<<agg_grid, 256, 0, stream>>>((const uint4*)h0b, offs, src, dis, tc + 128, (uint4*)h1b);
    // layer 2
    k_gemm<0><<<gemm_grid, 256, 0, stream>>>((const void*)h1b, WT + 2 * 16384, dis, h0b);
    k_agg<<<agg_grid, 256, 0, stream>>>((const uint4*)h0b, offs, src, dis, tc + 256, (uint4*)h1b);

    k_pool<<<(NN + PPN - 1) / PPN, 64, 0, stream>>>((const u32*)h1b, batch, pooled, counts);
    k_head<<<(GG * CC + 255) / 256, 256, 0, stream>>>(pooled, counts, lw, lb, out);
}

// Round 9
// 400.447 us; speedup vs baseline: 1.0913x; 1.0913x over previous
//
#include <hip/hip_runtime.h>
#include <hip/hip_bf16.h>

#define NN 100000
#define EE 1600000
#define DD 128
#define GG 128
#define CC 10
#define NPB 256      // nodes per bucket (power of 2)
#define NB 391       // ceil(NN/NPB)
#define SCAP 5120    // LDS slot capacity per bucket (mean 4092, sigma ~64)
#define VPT 16       // edges per thread in k_bcount/k_part
#define CPAD 32      // padded counter stride (ints) = 128B per counter
#define PPN 64       // nodes per pool block

typedef __attribute__((ext_vector_type(8))) short bf16x8;
typedef __attribute__((ext_vector_type(4))) float f32x4;
typedef unsigned int u32;

__device__ inline float blo(u32 u) { return __uint_as_float(u << 16); }
__device__ inline float bhi(u32 u) { return __uint_as_float(u & 0xffff0000u); }
// pack two floats to bf16x2 (RNE)
__device__ inline u32 bpack(float x, float y) {
    u32 bx = __float_as_uint(x);
    u32 by = __float_as_uint(y);
    bx = (bx + 0x7fffu + ((bx >> 16) & 1u)) >> 16;
    by = (by + 0x7fffu + ((by >> 16) & 1u)) & 0xffff0000u;
    return bx | by;
}

// ---------- bucket histogram: block-aggregated, padded counters ----------
__global__ __launch_bounds__(256) void k_bcount(const int* __restrict__ col,
                                                int* __restrict__ bhist) {
    __shared__ int lh[NB];
    int tid = threadIdx.x;
    for (int b = tid; b < NB; b += 256) lh[b] = 0;
    __syncthreads();
    int base = blockIdx.x * (256 * VPT);
#pragma unroll
    for (int j = 0; j < VPT; j++) {
        int e = base + j * 256 + tid;
        if (e < EE) atomicAdd(&lh[col[e] >> 8], 1);
    }
    __syncthreads();
    for (int b = tid; b < NB; b += 256) {
        int h = lh[b];
        if (h) atomicAdd(&bhist[b * CPAD], h);
    }
}

// ---------- bucket exclusive scan (single block, 512 threads) ----------
__global__ __launch_bounds__(512) void k_bscan(const int* __restrict__ bhist,
                                               int* __restrict__ boffs,
                                               int* __restrict__ bcur) {
    __shared__ int s[512];
    int tid = threadIdx.x;
    int c = (tid < NB) ? bhist[tid * CPAD] : 0;
    s[tid] = c;
    __syncthreads();
    for (int off = 1; off < 512; off <<= 1) {
        int v = (tid >= off) ? s[tid - off] : 0;
        __syncthreads();
        s[tid] += v;
        __syncthreads();
    }
    int excl = s[tid] - c;
    if (tid < NB) {
        boffs[tid] = excl;
        bcur[tid * CPAD] = excl;
    }
    if (tid == NB - 1) boffs[NB] = excl + c;  // == EE
}

// ---------- partition edges into bucket regions (packed r<<8 | c&255) ----------
__global__ __launch_bounds__(256) void k_part(const int* __restrict__ row, const int* __restrict__ col,
                                              int* __restrict__ bcur, u32* __restrict__ pairs) {
    __shared__ int lhist[NB];
    __shared__ int gbase[NB];
    __shared__ int lcur[NB];
    int tid = threadIdx.x;
    for (int b = tid; b < NB; b += 256) lhist[b] = 0;
    __syncthreads();
    int base = blockIdx.x * (256 * VPT);
    u32 v[VPT];
    int bb[VPT];
#pragma unroll
    for (int j = 0; j < VPT; j++) {
        int e = base + j * 256 + tid;
        if (e < EE) {
            int r = row[e], c = col[e];
            v[j] = ((u32)r << 8) | (u32)(c & 255);
            bb[j] = c >> 8;
            atomicAdd(&lhist[bb[j]], 1);
        } else {
            bb[j] = -1;
        }
    }
    __syncthreads();
    for (int b = tid; b < NB; b += 256) {
        int h = lhist[b];
        gbase[b] = h ? atomicAdd(&bcur[b * CPAD], h) : 0;
        lcur[b] = 0;
    }
    __syncthreads();
#pragma unroll
    for (int j = 0; j < VPT; j++) {
        if (bb[j] >= 0) {
            int slot = gbase[bb[j]] + atomicAdd(&lcur[bb[j]], 1);
            pairs[slot] = v[j];
        }
    }
}

// ---------- per-bucket: node counts -> offs+dis, LDS counting sort -> src ----------
__global__ __launch_bounds__(256) void k_sort(const u32* __restrict__ pairs,
                                              const int* __restrict__ boffs,
                                              int* __restrict__ offs,
                                              float* __restrict__ dis,
                                              int* __restrict__ src) {
    int b = blockIdx.x;
    int tid = threadIdx.x;
    int nstart = b << 8;
    int nvalid = NN - nstart;           // valid nodes in this bucket
    if (nvalid > NPB) nvalid = NPB;
    int base = boffs[b];
    int eend = boffs[b + 1];
    int cnt = eend - base;
    __shared__ int lcnt[NPB];
    __shared__ int lscan[NPB];
    __shared__ int lcur[NPB];
    __shared__ int lsrc[SCAP];
    lcnt[tid] = 0;
    __syncthreads();
    for (int e = base + tid; e < eend; e += 256)
        atomicAdd(&lcnt[pairs[e] & 255u], 1);
    __syncthreads();
    int c = lcnt[tid];
    lscan[tid] = c;
    __syncthreads();
    for (int off = 1; off < 256; off <<= 1) {
        int v = (tid >= off) ? lscan[tid - off] : 0;
        __syncthreads();
        lscan[tid] += v;
        __syncthreads();
    }
    int excl = lscan[tid] - c;
    if (tid < nvalid) {
        offs[nstart + tid] = base + excl;
        dis[nstart + tid] = rsqrtf((float)(c + 1));  // degree includes self-loop
    }
    if (b == NB - 1 && tid == 255) offs[NN] = EE;
    lcur[tid] = excl;
    __syncthreads();
    if (cnt <= SCAP) {
        for (int e = base + tid; e < eend; e += 256) {
            u32 v = pairs[e];
            int slot = atomicAdd(&lcur[v & 255u], 1);
            lsrc[slot] = (int)(v >> 8);
        }
        __syncthreads();
        for (int i = tid; i < cnt; i += 256)
            src[base + i] = lsrc[i];
    } else {
        // fallback (not expected on this input): place directly to global
        for (int e = base + tid; e < eend; e += 256) {
            u32 v = pairs[e];
            int slot = base + atomicAdd(&lcur[v & 255u], 1);
            src[slot] = (int)(v >> 8);
        }
    }
}

// ---------- params prep: W^T -> bf16 with BN scale folded into columns ----------
__global__ void k_prep(const float* __restrict__ Wc, const float* __restrict__ bc,
                       const float* __restrict__ gamma, const float* __restrict__ beta,
                       const float* __restrict__ mean, const float* __restrict__ var,
                       __hip_bfloat16* __restrict__ WT,
                       float* __restrict__ tc) {
    int i = blockIdx.x * 256 + threadIdx.x;
    if (i < 3 * 128) {
        int l = i >> 7, d = i & 127;
        float t;
        if (l < 2) {
            float s = gamma[l * 128 + d] * rsqrtf(var[l * 128 + d] + 1e-5f);
            t = (bc[l * 128 + d] - mean[l * 128 + d]) * s + beta[l * 128 + d];
        } else {
            t = bc[2 * 128 + d];
        }
        tc[i] = t;
    }
    if (i < 3 * 16384) {
        int l = i >> 14, r = (i >> 7) & 127, k = i & 127;
        float s = 1.f;
        if (l < 2) s = gamma[l * 128 + r] * rsqrtf(var[l * 128 + r] + 1e-5f);
        // WT[l][r][k] = W[l][k][r] * sc[l][r]  (BN scale folded into output column)
        WT[i] = __float2bfloat16(Wc[l * 16384 + k * 128 + r] * s);
    }
}

// ---------- GEMM: hs[N,128] = dis[n] * (A[N,128] @ (W*sc)), bf16 MFMA ----------
template <int FP32IN>
__global__ __launch_bounds__(256) void k_gemm(const void* __restrict__ Ain,
                                              const __hip_bfloat16* __restrict__ WT,
                                              const float* __restrict__ dis,
                                              __hip_bfloat16* __restrict__ Cout) {
    int wave = threadIdx.x >> 6, lane = threadIdx.x & 63;
    int lg = lane >> 4, lr = lane & 15;
    int r0w = blockIdx.x * 64 + wave * 16;
    f32x4 zero = {0.f, 0.f, 0.f, 0.f};
    f32x4 acc[8];
#pragma unroll
    for (int ct = 0; ct < 8; ct++) acc[ct] = zero;

    int arow = r0w + lr;
    if (arow > NN - 1) arow = NN - 1;

#pragma unroll
    for (int kk = 0; kk < 4; kk++) {
        bf16x8 a;
        if (FP32IN) {
            const float* ap = (const float*)Ain + (size_t)arow * 128 + kk * 32 + lg * 8;
            float4 f0 = *(const float4*)ap;
            float4 f1 = *(const float4*)(ap + 4);
            u32 t0 = bpack(f0.x, f0.y), t1 = bpack(f0.z, f0.w);
            u32 t2 = bpack(f1.x, f1.y), t3 = bpack(f1.z, f1.w);
            uint4 t = make_uint4(t0, t1, t2, t3);
            a = *(bf16x8*)&t;
        } else {
            a = *(const bf16x8*)((const __hip_bfloat16*)Ain + (size_t)arow * 128 + kk * 32 + lg * 8);
        }
#pragma unroll
        for (int ct = 0; ct < 8; ct++) {
            bf16x8 b = *(const bf16x8*)(WT + (size_t)(ct * 16 + lr) * 128 + kk * 32 + lg * 8);
            acc[ct] = __builtin_amdgcn_mfma_f32_16x16x32_bf16(a, b, acc[ct], 0, 0, 0);
        }
    }
    // C/D layout: col = lane&15, row = (lane>>4)*4 + reg
    float dv[4];
#pragma unroll
    for (int r = 0; r < 4; r++) {
        int row = r0w + lg * 4 + r;
        dv[r] = (row < NN) ? dis[row] : 0.f;
    }
#pragma unroll
    for (int ct = 0; ct < 8; ct++) {
#pragma unroll
        for (int r = 0; r < 4; r++) {
            int row = r0w + lg * 4 + r;
            if (row < NN) Cout[(size_t)row * 128 + ct * 16 + lr] = __float2bfloat16(acc[ct][r] * dv[r]);
        }
    }
}

// ---------- aggregation: h_out = LReLU(dis[c]*(sum(hs[src]) + hs[c]) + tc) ----------
// one wave per node; 64 lanes cover the full 256B row (one base per VMEM instr);
// src index explicitly scalarized -> SGPR-base loads, address math on scalar pipe.
__global__ __launch_bounds__(256) void k_agg(const u32* __restrict__ hin,
                                             const int* __restrict__ offs,
                                             const int* __restrict__ src,
                                             const float* __restrict__ dis,
                                             const float* __restrict__ tc,
                                             u32* __restrict__ hout) {
    int node = (blockIdx.x << 2) + (threadIdx.x >> 6);
    int lane = threadIdx.x & 63;
    if (node >= NN) return;
    int e0 = __builtin_amdgcn_readfirstlane(offs[node]);
    int e1 = __builtin_amdgcn_readfirstlane(offs[node + 1]);
    u32 self = hin[((u32)node << 6) + lane];          // self-loop contribution
    float a0 = blo(self), a1 = bhi(self);
    for (int e = e0; e < e1; e += 8) {
        int lim = e1 - e;  // wave-uniform
        u32 u[8];
#pragma unroll
        for (int j = 0; j < 8; j++) {
            int s = (j < lim) ? src[e + j] : node;
            s = __builtin_amdgcn_readfirstlane(s);    // SGPR base for the row load
            u[j] = hin[((u32)s << 6) + lane];
        }
#pragma unroll
        for (int j = 0; j < 8; j++) {
            if (j < lim) { a0 += blo(u[j]); a1 += bhi(u[j]); }
        }
    }
    float dn = dis[node];
    int d0 = lane * 2;
    float r0 = a0 * dn + tc[d0];
    float r1 = a1 * dn + tc[d0 + 1];
    r0 = r0 > 0.f ? r0 : 0.03f * r0;
    r1 = r1 > 0.f ? r1 : 0.03f * r1;
    hout[((u32)node << 6) + lane] = bpack(r0, r1);
}

// ---------- global mean pool: parallel partial sums (batch sorted) ----------
__global__ __launch_bounds__(64) void k_pool(const u32* __restrict__ h,
                                             const int* __restrict__ batch,
                                             float* __restrict__ pooled,
                                             float* __restrict__ counts) {
    int lane = threadIdx.x;  // covers 2 feature cols
    int n0 = blockIdx.x * PPN;
    if (n0 >= NN) return;
    int n1 = n0 + PPN;
    if (n1 > NN) n1 = NN;
    float a0 = 0.f, a1 = 0.f, cnt = 0.f;
    int g = batch[n0];
    for (int n = n0; n < n1; n++) {
        int bg = batch[n];
        if (bg != g) {
            atomicAdd(&pooled[g * 128 + lane * 2], a0);
            atomicAdd(&pooled[g * 128 + lane * 2 + 1], a1);
            if (lane == 0) atomicAdd(&counts[g], cnt);
            a0 = 0.f; a1 = 0.f; cnt = 0.f; g = bg;
        }
        u32 u = h[(u32)n * 64u + lane];
        a0 += blo(u); a1 += bhi(u);
        cnt += 1.f;
    }
    atomicAdd(&pooled[g * 128 + lane * 2], a0);
    atomicAdd(&pooled[g * 128 + lane * 2 + 1], a1);
    if (lane == 0) atomicAdd(&counts[g], cnt);
}

// ---------- head ----------
__global__ void k_head(const float* __restrict__ pooled, const float* __restrict__ counts,
                       const float* __restrict__ w, const float* __restrict__ b,
                       float* __restrict__ out) {
    int i = blockIdx.x * blockDim.x + threadIdx.x;
    if (i >= GG * CC) return;
    int g = i / CC, c = i % CC;
    float cnt = counts[g];
    cnt = cnt > 1.f ? cnt : 1.f;
    float inv = 1.f / cnt;
    const float* p = &pooled[g * 128];
    const float* ww = &w[c * 128];
    float acc = 0.f;
    for (int d = 0; d < 128; d++) acc += p[d] * ww[d];
    out[i] = acc * inv + b[c];
}

extern "C" void kernel_launch(void* const* d_in, const int* in_sizes, int n_in,
                              void* d_out, int out_size, void* d_ws, size_t ws_size,
                              hipStream_t stream) {
    const float* x     = (const float*)d_in[0];
    const int*   ei    = (const int*)d_in[1];
    const int*   row   = ei;
    const int*   col   = ei + EE;
    const int*   batch = (const int*)d_in[2];
    const float* Wc    = (const float*)d_in[3];
    const float* bc    = (const float*)d_in[4];
    const float* gamma = (const float*)d_in[5];
    const float* beta  = (const float*)d_in[6];
    const float* mean  = (const float*)d_in[7];
    const float* var   = (const float*)d_in[8];
    const float* lw    = (const float*)d_in[9];
    const float* lb    = (const float*)d_in[10];
    float* out = (float*)d_out;

    char* p = (char*)d_ws;
    auto alloc = [&](size_t bytes) -> char* {
        char* r = p;
        p += (bytes + 255) & ~(size_t)255;
        return r;
    };
    float* dis    = (float*)alloc((size_t)NN * 4);
    int*   offs   = (int*)alloc((size_t)(NN + 1) * 4);
    int*   bhist  = (int*)alloc((size_t)NB * CPAD * 4);
    int*   boffs  = (int*)alloc((size_t)(NB + 1) * 4);
    int*   bcur   = (int*)alloc((size_t)NB * CPAD * 4);
    int*   src    = (int*)alloc((size_t)EE * 4);
    __hip_bfloat16* WT = (__hip_bfloat16*)alloc((size_t)3 * 16384 * 2);
    float* tc     = (float*)alloc((size_t)3 * 128 * 4);
    float* pooled = (float*)alloc((size_t)GG * 128 * 4);
    float* counts = (float*)alloc((size_t)GG * 4);
    __hip_bfloat16* h0b = (__hip_bfloat16*)alloc((size_t)NN * 128 * 2);
    __hip_bfloat16* h1b = (__hip_bfloat16*)alloc((size_t)NN * 128 * 2);
    u32* pairs = (u32*)h0b;  // alias: pairs dead before first k_gemm writes h0b

    hipMemsetAsync(bhist, 0, (size_t)NB * CPAD * 4, stream);
    hipMemsetAsync(pooled, 0, (size_t)GG * 128 * 4, stream);
    hipMemsetAsync(counts, 0, (size_t)GG * 4, stream);

    const int eb_grid = (EE + 256 * VPT - 1) / (256 * VPT);
    k_bcount<<<eb_grid, 256, 0, stream>>>(col, bhist);
    k_bscan<<<1, 512, 0, stream>>>(bhist, boffs, bcur);
    k_part<<<eb_grid, 256, 0, stream>>>(row, col, bcur, pairs);
    k_sort<<<NB, 256, 0, stream>>>(pairs, boffs, offs, dis, src);
    k_prep<<<192, 256, 0, stream>>>(Wc, bc, gamma, beta, mean, var, WT, tc);

    const int gemm_grid = (NN + 63) / 64;
    const int agg_grid  = (NN + 3) / 4;

    // layer 0: A = x (fp32)
    k_gemm<1><<<gemm_grid, 256, 0, stream>>>((const void*)x, WT, dis, h0b);
    k_agg<<<agg_grid, 256, 0, stream>>>((const u32*)h0b, offs, src, dis, tc, (u32*)h1b);
    // layer 1
    k_gemm<0><<<gemm_grid, 256, 0, stream>>>((const void*)h1b, WT + 16384, dis, h0b);
    k_agg<<<agg_grid, 256, 0, stream>>>((const u32*)h0b, offs, src, dis, tc + 128, (u32*)h1b);
    // layer 2
    k_gemm<0><<<gemm_grid, 256, 0, stream>>>((const void*)h1b, WT + 2 * 16384, dis, h0b);
    k_agg<<<agg_grid, 256, 0, stream>>>((const u32*)h0b, offs, src, dis, tc + 256, (u32*)h1b);

    k_pool<<<(NN + PPN - 1) / PPN, 64, 0, stream>>>((const u32*)h1b, batch, pooled, counts);
    k_head<<<(GG * CC + 255) / 256, 256, 0, stream>>>(pooled, counts, lw, lb, out);
}